// Round 4
// baseline (63.062 us; speedup 1.0000x reference)
//
#include <hip/hip_runtime.h>
#include <cstdint>

typedef __bf16 bf16x8 __attribute__((ext_vector_type(8)));
typedef float f32x4 __attribute__((ext_vector_type(4)));
typedef unsigned short u16;

#define NROWS 4096
#define DIM 512
#define ZROWS 8192
#define BT 256       /* tile edge */
#define BK 64
#define NT2 32       /* 8192/256 */
#define NB2 528      /* 32*33/2 upper-triangular tile pairs */
#define CH2 66       /* NB2/8 — bijective XCD swizzle */

// ---------------- kernel 1: f32 -> bf16 + row norms (from bf16-rounded values) ----
__global__ __launch_bounds__(256) void prep_kernel(const float* __restrict__ lbl,
                                                   const float* __restrict__ pred,
                                                   u16* __restrict__ zb,
                                                   float* __restrict__ xnorm) {
    const int w = threadIdx.x >> 6;
    const int l = threadIdx.x & 63;
    const int row = blockIdx.x * 4 + w;
    const float* src = (row < NROWS) ? (lbl + (size_t)row * DIM)
                                     : (pred + (size_t)(row - NROWS) * DIM);
    const float4 v0 = *(const float4*)(src + l * 8);
    const float4 v1 = *(const float4*)(src + l * 8 + 4);
    float f[8] = {v0.x, v0.y, v0.z, v0.w, v1.x, v1.y, v1.z, v1.w};
    uint32_t pk[4];
    float nrm = 0.f;
#pragma unroll
    for (int j = 0; j < 4; ++j) {
        uint32_t b0 = __float_as_uint(f[2 * j]);
        uint32_t b1 = __float_as_uint(f[2 * j + 1]);
        uint32_t r0 = (b0 + 0x7fffu + ((b0 >> 16) & 1u)) >> 16;  // RNE to bf16
        uint32_t r1 = (b1 + 0x7fffu + ((b1 >> 16) & 1u)) >> 16;
        pk[j] = r0 | (r1 << 16);
        float fb0 = __uint_as_float(r0 << 16);
        float fb1 = __uint_as_float(r1 << 16);
        nrm += fb0 * fb0 + fb1 * fb1;
    }
    *(uint4*)(zb + (size_t)row * DIM + l * 8) = make_uint4(pk[0], pk[1], pk[2], pk[3]);
#pragma unroll
    for (int off = 32; off; off >>= 1) nrm += __shfl_xor(nrm, off);
    if (l == 0) xnorm[row] = nrm;
}

// ---------------- kernel 2: 256x256-tile 8-phase Z Z^T + fused exp/reduce ---------
// 8 waves (2M x 4N), wave tile 128x64, acc[8][4]. LDS 128 KiB:
//   [op A/B][buf][half][128 rows][64 bf16 = 128 B], st-swizzle slot^=(row&7).
// Per iter (2 K-tiles, 8 phases): snake quadrants Q00,Q01,Q11,Q10 per K-tile;
// stage cadence P1,P2:A(kt+1)->buf1  P3,P4:B(kt+2)->buf0  P5,P6:A(kt+2)->buf0
// P7,P8:B(kt+3)->buf1 (each half issued only after its slot's last reader's
// barrier). Counted vmcnt(4) at P4/P8 only (2 loads/half: 4 youngest = the 2
// not-yet-needed halves). T5 setprio around MFMA clusters.
__global__ __launch_bounds__(512, 2) void mmd_gemm_kernel(const u16* __restrict__ zb,
                                                          const float* __restrict__ xnorm,
                                                          float* __restrict__ partials) {
    __shared__ u16 lds[2][2][2][8192];  // [op][buf][half][128*64] — 131072 B

    const int bid = (int)blockIdx.x;
    const int sbid = (bid & 7) * CH2 + (bid >> 3);
    int bm = 0, rem = sbid;
    while (rem >= (NT2 - bm)) { rem -= NT2 - bm; ++bm; }
    const int bn = bm + rem;
    const bool diag = (bm == bn);

    const int tid = threadIdx.x;
    const int wv = tid >> 6;
    const int l = tid & 63;
    const int wr = wv >> 2, wc = wv & 3;

    const char* zbytes = (const char*)zb;

    // ---- staging (global_load_lds, 16 B/lane; pre-swizzled source slot) ----
    const int sr = tid >> 3;                             // LDS row (j=0) within half
    const int csl = ((tid ^ (tid >> 3)) & 7) << 4;       // slot ^ (row&7), row&7=(tid>>3)&7
    auto STG = [&](int op, int buf, int half, int kt) {
        const int rowg0 = (op ? bn : bm) * BT + half * 128;
#pragma unroll
        for (int j = 0; j < 2; ++j) {
            const int r = j * 64 + sr;
            const char* src = zbytes + (size_t)(rowg0 + r) * (DIM * 2) + kt * 128 + csl;
            char* dst = (char*)&lds[op][buf][half][0] + j * 8192 + tid * 16;
            __builtin_amdgcn_global_load_lds((const __attribute__((address_space(1))) void*)src,
                                             (__attribute__((address_space(3))) void*)dst, 16, 0, 0);
        }
    };

    // ---- fragment loads (swizzled ds_read; row&7 == l&7 for all frags) ----
    const int rl = l & 15;
    const int k0 = ((((l >> 4) ^ l) & 7) << 4);        // kk=0 slot byte
    const int k1 = ((((4 + (l >> 4)) ^ l) & 7) << 4);  // kk=1 slot byte
    bf16x8 aR[4][2], b0[2][2], b1[2][2];
    auto LDA_ = [&](int buf, int mh) {
        const char* base = (const char*)&lds[0][buf][wr][0] + (mh * 64 + rl) * 128;
#pragma unroll
        for (int mm = 0; mm < 4; ++mm) {
            aR[mm][0] = *(const bf16x8*)(base + mm * 2048 + k0);
            aR[mm][1] = *(const bf16x8*)(base + mm * 2048 + k1);
        }
    };
    auto LDB_ = [&](int buf, int nh, bf16x8 (&bb)[2][2]) {
        const char* base = (const char*)&lds[1][buf][wc >> 1][0] + ((wc & 1) * 64 + nh * 32 + rl) * 128;
#pragma unroll
        for (int nn = 0; nn < 2; ++nn) {
            bb[nn][0] = *(const bf16x8*)(base + nn * 2048 + k0);
            bb[nn][1] = *(const bf16x8*)(base + nn * 2048 + k1);
        }
    };

    f32x4 acc[8][4];
#pragma unroll
    for (int m = 0; m < 8; ++m)
#pragma unroll
        for (int n = 0; n < 4; ++n) acc[m][n] = (f32x4){0.f, 0.f, 0.f, 0.f};

    auto MM_ = [&](int mq, int nq, bf16x8 (&bb)[2][2]) {
#pragma unroll
        for (int kk = 0; kk < 2; ++kk)
#pragma unroll
            for (int mm = 0; mm < 4; ++mm)
#pragma unroll
                for (int nn = 0; nn < 2; ++nn)
                    acc[mq * 4 + mm][nq * 2 + nn] = __builtin_amdgcn_mfma_f32_16x16x32_bf16(
                        aR[mm][kk], bb[nn][kk], acc[mq * 4 + mm][nq * 2 + nn], 0, 0, 0);
    };

#define PH_MID() do { __builtin_amdgcn_s_barrier(); \
    asm volatile("s_waitcnt lgkmcnt(0)" ::: "memory"); \
    __builtin_amdgcn_sched_barrier(0); \
    __builtin_amdgcn_s_setprio(1); } while (0)
#define PH_END() do { __builtin_amdgcn_s_setprio(0); \
    __builtin_amdgcn_s_barrier(); } while (0)

    auto ITER = [&](int ko, bool hn) {
        // P1: Q00 of kt=ko (buf0); stage A-h0(ko+1)->buf1
        asm volatile("" ::: "memory");
        LDA_(0, 0); LDB_(0, 0, b0);
        STG(0, 1, 0, ko + 1);
        PH_MID(); MM_(0, 0, b0); PH_END();
        // P2: Q01; stage A-h1(ko+1)->buf1
        asm volatile("" ::: "memory");
        LDB_(0, 1, b1);
        STG(0, 1, 1, ko + 1);
        PH_MID(); MM_(0, 1, b1); PH_END();
        // P3: Q11; stage B-h0(ko+2)->buf0
        asm volatile("" ::: "memory");
        LDA_(0, 1);
        if (hn) STG(1, 0, 0, ko + 2);
        PH_MID(); MM_(1, 1, b1); PH_END();
        // P4: Q10; stage B-h1(ko+2)->buf0; vmcnt gate
        asm volatile("" ::: "memory");
        if (hn) {
            STG(1, 0, 1, ko + 2);
            asm volatile("s_waitcnt vmcnt(4)" ::: "memory");
        } else {
            asm volatile("s_waitcnt vmcnt(0)" ::: "memory");
        }
        __builtin_amdgcn_s_barrier();
        __builtin_amdgcn_s_setprio(1);
        MM_(1, 0, b0);
        PH_END();
        // P5: Q00 of kt=ko+1 (buf1); stage A-h0(ko+2)->buf0
        asm volatile("" ::: "memory");
        LDA_(1, 0); LDB_(1, 0, b0);
        if (hn) STG(0, 0, 0, ko + 2);
        PH_MID(); MM_(0, 0, b0); PH_END();
        // P6: Q01; stage A-h1(ko+2)->buf0
        asm volatile("" ::: "memory");
        LDB_(1, 1, b1);
        if (hn) STG(0, 0, 1, ko + 2);
        PH_MID(); MM_(0, 1, b1); PH_END();
        // P7: Q11; stage B-h0(ko+3)->buf1
        asm volatile("" ::: "memory");
        LDA_(1, 1);
        if (hn) STG(1, 1, 0, ko + 3);
        PH_MID(); MM_(1, 1, b1); PH_END();
        // P8: Q10; stage B-h1(ko+3)->buf1; vmcnt gate
        asm volatile("" ::: "memory");
        if (hn) {
            STG(1, 1, 1, ko + 3);
            asm volatile("s_waitcnt vmcnt(4)" ::: "memory");
        }
        __builtin_amdgcn_s_barrier();
        __builtin_amdgcn_s_setprio(1);
        MM_(1, 0, b0);
        PH_END();
    };

    // prologue: buf0 <- kt0 (A,B); buf1 <- B(kt1). A(kt1) arrives at iter0 P1/P2.
    STG(0, 0, 0, 0); STG(0, 0, 1, 0);
    STG(1, 0, 0, 0); STG(1, 0, 1, 0);
    STG(1, 1, 0, 1); STG(1, 1, 1, 1);
    asm volatile("s_waitcnt vmcnt(0)" ::: "memory");
    __builtin_amdgcn_s_barrier();

    for (int i = 0; i < 3; ++i) ITER(2 * i, true);
    ITER(6, false);

    // ---- epilogue: dist = xi + xj - 2*c ; term = exp2(-d/(2 ln2)) -----------
    __syncthreads();
    float xjv[4];
    const int baseJ = bn * BT + wc * 64 + (l & 15);
#pragma unroll
    for (int n = 0; n < 4; ++n) xjv[n] = xnorm[baseJ + n * 16];
    const int baseI = bm * BT + wr * 128 + (l >> 4) * 4;
    float local = 0.f;
#pragma unroll
    for (int m = 0; m < 8; ++m) {
        const float4 xi = *(const float4*)(xnorm + baseI + m * 16);
#pragma unroll
        for (int n = 0; n < 4; ++n) {
            float d0 = (xi.x + xjv[n]) - 2.f * acc[m][n][0];
            float d1 = (xi.y + xjv[n]) - 2.f * acc[m][n][1];
            float d2 = (xi.z + xjv[n]) - 2.f * acc[m][n][2];
            float d3 = (xi.w + xjv[n]) - 2.f * acc[m][n][3];
            float dmin = fminf(fminf(d0, d1), fminf(d2, d3));
            if (dmin < 40.f) {  // d>40 => term < 2.1e-9 summed — provable skip
                local += exp2f(-0.72134752f * d0);
                local += exp2f(-0.72134752f * d1);
                local += exp2f(-0.72134752f * d2);
                local += exp2f(-0.72134752f * d3);
            }
        }
    }
    const float sgn = ((bm < 16) == (bn < 16)) ? 1.f : -1.f;  // block-uniform signs
    local *= sgn * (diag ? 1.f : 2.f);
#pragma unroll
    for (int off = 32; off; off >>= 1) local += __shfl_xor(local, off);
    float* red = (float*)&lds[0][0][0][0];  // reuse LDS post-barrier
    if (l == 0) red[wv] = local;
    __syncthreads();
    if (tid == 0) {
        float s = 0.f;
#pragma unroll
        for (int q = 0; q < 8; ++q) s += red[q];
        partials[sbid] = s;
    }
}

// ---------------- kernel 3: deterministic final reduce ---------------------------
__global__ __launch_bounds__(256) void reduce_kernel(const float* __restrict__ partials,
                                                     float* __restrict__ out, int n) {
    __shared__ float red[4];
    float s = 0.f;
    for (int i = threadIdx.x; i < n; i += 256) s += partials[i];
#pragma unroll
    for (int off = 32; off; off >>= 1) s += __shfl_xor(s, off);
    if ((threadIdx.x & 63) == 0) red[threadIdx.x >> 6] = s;
    __syncthreads();
    if (threadIdx.x == 0)
        out[0] = (red[0] + red[1] + red[2] + red[3]) * (1.f / 16777216.f);  // / 4096^2
}

extern "C" void kernel_launch(void* const* d_in, const int* in_sizes, int n_in,
                              void* d_out, int out_size, void* d_ws, size_t ws_size,
                              hipStream_t stream) {
    const float* lbl = (const float*)d_in[0];
    const float* pred = (const float*)d_in[1];
    u16* zb = (u16*)d_ws;
    float* xnorm = (float*)((char*)d_ws + (size_t)ZROWS * DIM * 2);
    float* partials = (float*)((char*)d_ws + (size_t)ZROWS * DIM * 2 + (size_t)ZROWS * 4);

    prep_kernel<<<ZROWS / 4, 256, 0, stream>>>(lbl, pred, zb, xnorm);
    mmd_gemm_kernel<<<NB2, 512, 0, stream>>>(zb, xnorm, partials);
    reduce_kernel<<<1, 256, 0, stream>>>(partials, (float*)d_out, NB2);
}